// Round 11
// baseline (115.895 us; speedup 1.0000x reference)
//
#include <hip/hip_runtime.h>

// GenomeNet: B=4096, N_IN=W=N_OUT=1024, L=8 hidden, D=16 fan-in.
// R11 = R10 (compile fix: cvt_pkrtz returns __fp16x2 — bit_cast to h2v).
// Structure: R5/R6 (TB=8, fp16 16B rows, bank-group=s%8, 512 blocks x
// 1024 thr, 2 blocks/CU, 4608 ds_read_b128/CU = instruction floor) with the
// inner math rebuilt to halve VALU issue pressure: edges paired (d,d+1),
// lane-local half2 (edge0[j],edge1[j]) built with v_perm_b32, weights packed
// with v_cvt_pkrtz, accumulation via v_dot2_f32_f16 (f32 accumulate: exact).
// Per edge-pair ~17 VALU vs 32 (cvt+fma). Theory: DS pipe is 75% utilized;
// the idle 25% is VALU/DS issue contention, not conflicts (data-inherent,
// R4/R8) nor ILP depth (R6/R9: compiler pins 2 loads in flight, VGPR=32).

#define TB       8
#define W_NODES  1024
#define LAYERS   8
#define ROW_H    8                     // halfs per node row (16 B)
#define BUF_H    (W_NODES * ROW_H)     // 8192 halfs = 16 KB

typedef _Float16 h2v __attribute__((ext_vector_type(2)));

__device__ __forceinline__ float fast_tanh(float x) {
    // tanh(x) = 1 - 2/(e^{2x}+1)
    float a = __builtin_amdgcn_exp2f(x * 2.8853900817779268f);
    return 1.0f - 2.0f * __builtin_amdgcn_rcpf(a + 1.0f);
}

__device__ __forceinline__ h2v pack2(float a, float b) {
    return __builtin_bit_cast(h2v, __builtin_amdgcn_cvt_pkrtz(a, b));
}

__device__ __forceinline__ unsigned pack2u(float a, float b) {
    return __builtin_bit_cast(unsigned, __builtin_amdgcn_cvt_pkrtz(a, b));
}

__device__ __forceinline__ float fdot2(h2v a, h2v b, float c) {
#if __has_builtin(__builtin_amdgcn_fdot2)
    return __builtin_amdgcn_fdot2(a, b, c, false);
#else
    return fmaf((float)a[0], (float)b[0], fmaf((float)a[1], (float)b[1], c));
#endif
}

// 16 edge-gathers as 8 pairs; acc[j] += e0[j]*w0 + e1[j]*w1 via v_dot2_f32_f16.
// v_perm_b32(S0=g1,S1=g0): sel bytes 0-3 pick from g0, 4-7 from g1.
// lo = (g0.low16, g1.low16) = batches 2k; hi = (g0.high16, g1.high16) = 2k+1.
__device__ __forceinline__ void gather16(const _Float16* __restrict__ rd,
                                         const int* __restrict__ si,
                                         const float* __restrict__ wi,
                                         float* __restrict__ acc)
{
    #pragma unroll
    for (int p = 0; p < 8; ++p) {
        const uint4 g0 = *(const uint4*)(rd + (si[2*p]     << 3));
        const uint4 g1 = *(const uint4*)(rd + (si[2*p + 1] << 3));
        const h2v wp = pack2(wi[2*p], wi[2*p + 1]);
        const unsigned g0a[4] = {g0.x, g0.y, g0.z, g0.w};
        const unsigned g1a[4] = {g1.x, g1.y, g1.z, g1.w};
        #pragma unroll
        for (int k = 0; k < 4; ++k) {
            const unsigned lo = __builtin_amdgcn_perm(g1a[k], g0a[k], 0x05040100u);
            const unsigned hi = __builtin_amdgcn_perm(g1a[k], g0a[k], 0x07060302u);
            acc[2*k]     = fdot2(__builtin_bit_cast(h2v, lo), wp, acc[2*k]);
            acc[2*k + 1] = fdot2(__builtin_bit_cast(h2v, hi), wp, acc[2*k + 1]);
        }
    }
}

__global__ __launch_bounds__(1024, 8) void genome_net(
    const float* __restrict__ x,
    const int*   __restrict__ src_hidden,
    const float* __restrict__ w_hidden,
    const int*   __restrict__ src_out,
    const float* __restrict__ w_out,
    float*       __restrict__ out)
{
    extern __shared__ _Float16 lds[];
    _Float16* bufA = lds;              // [1024 nodes][8 batch] fp16, 16 KB
    _Float16* bufB = lds + BUF_H;

    const int t  = threadIdx.x;        // node / output index
    const int b0 = blockIdx.x * TB;    // batch tile base

    // ---- Stage x: fp32 -> fp16 row via cvt_pkrtz. Coalesced global loads.
    {
        float xv[TB];
        #pragma unroll
        for (int j = 0; j < TB; ++j)
            xv[j] = x[(size_t)(b0 + j) * W_NODES + t];
        uint4 st;
        st.x = pack2u(xv[0], xv[1]);
        st.y = pack2u(xv[2], xv[3]);
        st.z = pack2u(xv[4], xv[5]);
        st.w = pack2u(xv[6], xv[7]);
        *(uint4*)(bufA + t * ROW_H) = st;
    }
    __syncthreads();

    _Float16* rd = bufA;
    _Float16* wr = bufB;

    #pragma unroll 1
    for (int l = 0; l < LAYERS; ++l) {
        const int row = (l << 10) + t;
        const int4*   sp = (const int4*)(src_hidden) + (row << 2);
        const float4* wp = (const float4*)(w_hidden) + (row << 2);
        int4   s4[4]; float4 w4[4];
        #pragma unroll
        for (int q = 0; q < 4; ++q) { s4[q] = sp[q]; w4[q] = wp[q]; }
        int   si[16]; float wi[16];
        #pragma unroll
        for (int q = 0; q < 4; ++q) {
            si[4*q+0] = s4[q].x; si[4*q+1] = s4[q].y;
            si[4*q+2] = s4[q].z; si[4*q+3] = s4[q].w;
            wi[4*q+0] = w4[q].x; wi[4*q+1] = w4[q].y;
            wi[4*q+2] = w4[q].z; wi[4*q+3] = w4[q].w;
        }

        float acc[TB];
        #pragma unroll
        for (int j = 0; j < TB; ++j) acc[j] = 0.0f;

        gather16(rd, si, wi, acc);

        uint4 st;
        st.x = pack2u(fast_tanh(acc[0]), fast_tanh(acc[1]));
        st.y = pack2u(fast_tanh(acc[2]), fast_tanh(acc[3]));
        st.z = pack2u(fast_tanh(acc[4]), fast_tanh(acc[5]));
        st.w = pack2u(fast_tanh(acc[6]), fast_tanh(acc[7]));
        *(uint4*)(wr + t * ROW_H) = st;   // group = t%8: balanced write

        __syncthreads();
        _Float16* tmp = rd; rd = wr; wr = tmp;
    }

    // ---- Output layer: identity activation, fp32 accumulate + stores.
    {
        const int4*   sp = (const int4*)(src_out) + (t << 2);
        const float4* wp = (const float4*)(w_out) + (t << 2);
        int4   s4[4]; float4 w4[4];
        #pragma unroll
        for (int q = 0; q < 4; ++q) { s4[q] = sp[q]; w4[q] = wp[q]; }
        int   si[16]; float wi[16];
        #pragma unroll
        for (int q = 0; q < 4; ++q) {
            si[4*q+0] = s4[q].x; si[4*q+1] = s4[q].y;
            si[4*q+2] = s4[q].z; si[4*q+3] = s4[q].w;
            wi[4*q+0] = w4[q].x; wi[4*q+1] = w4[q].y;
            wi[4*q+2] = w4[q].z; wi[4*q+3] = w4[q].w;
        }

        float acc[TB];
        #pragma unroll
        for (int j = 0; j < TB; ++j) acc[j] = 0.0f;

        gather16(rd, si, wi, acc);

        // Coalesced 4 KB stores per j across the block.
        #pragma unroll
        for (int j = 0; j < TB; ++j)
            out[(size_t)(b0 + j) * W_NODES + t] = acc[j];
    }
}

extern "C" void kernel_launch(void* const* d_in, const int* in_sizes, int n_in,
                              void* d_out, int out_size, void* d_ws, size_t ws_size,
                              hipStream_t stream) {
    const float* x  = (const float*)d_in[0];
    const int*   sh = (const int*)  d_in[1];
    const float* wh = (const float*)d_in[2];
    const int*   so = (const int*)  d_in[3];
    const float* wo = (const float*)d_in[4];
    float* out = (float*)d_out;

    const int shmem = 2 * BUF_H * (int)sizeof(_Float16);   // 32768 B
    (void)hipFuncSetAttribute(reinterpret_cast<const void*>(genome_net),
                              hipFuncAttributeMaxDynamicSharedMemorySize, shmem);

    genome_net<<<dim3(4096 / TB), dim3(1024), shmem, stream>>>(
        x, sh, wh, so, wo, out);
}